// Round 3
// baseline (779.738 us; speedup 1.0000x reference)
//
#include <hip/hip_runtime.h>
#include <stdint.h>

// Problem constants (fixed by setup_inputs)
#define CCH 64
#define HW  (1024 * 1024)
#define NPIX (1024 * 1024)
#define NSEG 4096
#define NBIN 65536          // pos >> 4 buckets (one 64B feature line per bucket)

#define SLABS 16            // channel slabs, CPS channels each
#define CPS 4               // channels per slab -> 4096*4*4B = 64 KB LDS accumulators
#define RANGES 32           // sorted-entry ranges (32 -> 512 blocks)
#define EPR (NPIX / RANGES) // 32768 entries per range
#define BPT 4               // uint2 (= 8 entries) per thread per iter
#define NIT (EPR / (2048 * BPT))   // 4 iterations

// ws layout (KB offsets):
//      0  packed        u32[NPIX]              4096 KB
//   4096  sortedPos     u32[NPIX]              4096 KB
//   8192  poshist       u32[NBIN]               256 KB  \ one contiguous 512 KB memset
//   8448  seghistPad    u32[NSEG*16]            256 KB  /
//   8704  posLocal      u32[NBIN]               256 KB
//   8960  posBlk        u32[64]                   4 KB
//   9216  posCursorPad  u32[NBIN*16]           4096 KB
//  13312  partials      f32[RANGES*SLABS*16384] 32768 KB
//  46080  end
#define WS_NEED ((size_t)46080 * 1024)

// 2 entries per thread
__global__ void k1_pack_hist(const int4* __restrict__ pix2,
                             const int2* __restrict__ seg2,
                             uint2* __restrict__ packed2,
                             uint32_t* __restrict__ poshist,
                             uint32_t* __restrict__ seghistPad) {
    int n = blockIdx.x * blockDim.x + threadIdx.x;
    int4 yx = pix2[n];                    // (y0,x0,y1,x1)
    int2 ss = seg2[n];
    uint32_t pos0 = ((uint32_t)yx.x << 10) | (uint32_t)yx.y;
    uint32_t pos1 = ((uint32_t)yx.z << 10) | (uint32_t)yx.w;
    packed2[n] = make_uint2(((uint32_t)ss.x << 20) | pos0,
                            ((uint32_t)ss.y << 20) | pos1);
    atomicAdd(&poshist[pos0 >> 4], 1u);
    atomicAdd(&poshist[pos1 >> 4], 1u);
    atomicAdd(&seghistPad[(uint32_t)ss.x * 16], 1u);
    atomicAdd(&seghistPad[(uint32_t)ss.y * 16], 1u);
}

// 64 blocks x 1024: local inclusive scan of poshist -> local EXCLUSIVE + block total
__global__ void k2a_scan_local(const uint32_t* __restrict__ poshist,
                               uint32_t* __restrict__ posLocal,
                               uint32_t* __restrict__ posBlk) {
    __shared__ uint32_t sh[1024];
    int t = threadIdx.x, b = blockIdx.x;
    int i = b * 1024 + t;
    uint32_t v = poshist[i];
    sh[t] = v;
    __syncthreads();
    for (int off = 1; off < 1024; off <<= 1) {
        uint32_t u = (t >= off) ? sh[t - off] : 0u;
        __syncthreads();
        sh[t] += u;
        __syncthreads();
    }
    uint32_t inc = sh[t];
    posLocal[i] = inc - v;
    if (t == 1023) posBlk[b] = inc;
}

// 64 blocks x 1024: each block reduces posBlk[0..b) itself,
// then final cursor = local exclusive + block base, 1 bin / 64B line
__global__ void k2c_scan_add(const uint32_t* __restrict__ posLocal,
                             const uint32_t* __restrict__ posBlk,
                             uint32_t* __restrict__ posCursorPad) {
    __shared__ uint32_t sbase;
    int t = threadIdx.x, b = blockIdx.x;
    if (t < 64) {                                // wave 0
        uint32_t v = (t < b) ? posBlk[t] : 0u;
        for (int off = 32; off; off >>= 1) v += __shfl_down(v, off);
        if (t == 0) sbase = v;
    }
    __syncthreads();
    int i = b * 1024 + t;
    posCursorPad[(size_t)i * 16] = posLocal[i] + sbase;
}

// 2 entries per thread
__global__ void k3_scatter(const uint2* __restrict__ packed2,
                           uint32_t* __restrict__ posCursorPad,
                           uint32_t* __restrict__ sorted) {
    int n = blockIdx.x * blockDim.x + threadIdx.x;
    uint2 p = packed2[n];
    uint32_t d0 = atomicAdd(&posCursorPad[(size_t)((p.x & 0xFFFFFu) >> 4) * 16], 1u);
    uint32_t d1 = atomicAdd(&posCursorPad[(size_t)((p.y & 0xFFFFFu) >> 4) * 16], 1u);
    sorted[d0] = p.x;
    sorted[d1] = p.y;
}

// Main accumulate. Block = (range, slab). MLP by construction:
// per iteration, 8 entries x 4 channels = 32 independent gathers land in a
// fully-unrolled register block (static indices only), then a
// sched_barrier(0) fence, then the 32 LDS atomics. The fence forces all 32
// values live -> compiler must issue 32 back-to-back loads (~256 consecutive
// 64B lines in flight per wave). No loop-carried register rotation for the
// scheduler to collapse (the round-2 failure mode: VGPR=24 proved va/vb were
// folded and loads serialized at ~200cy each).
__global__ __launch_bounds__(1024) void k4_accum(const float* __restrict__ feat,
                                                 const uint32_t* __restrict__ sorted,
                                                 float* __restrict__ partials) {
    __shared__ float sums[CPS * NSEG];           // 64 KB
    const int tid = threadIdx.x;
    const int range = blockIdx.x >> 4;
    const int slab  = blockIdx.x & 15;
    for (int i = tid; i < CPS * NSEG; i += 1024) sums[i] = 0.f;

    const uint2* sp = (const uint2*)(sorted + (size_t)range * EPR);   // 16384 uint2
    const float* fbase = feat + (size_t)(slab * CPS) * HW;
    __syncthreads();

    for (int it = 0; it < NIT; ++it) {
        uint2 E[BPT];
#pragma unroll
        for (int k = 0; k < BPT; ++k)
            E[k] = sp[it * (BPT * 1024) + k * 1024 + tid];   // coalesced

        float v[BPT][2][CPS];
#pragma unroll
        for (int k = 0; k < BPT; ++k) {
            uint32_t p0 = E[k].x & 0xFFFFFu, p1 = E[k].y & 0xFFFFFu;
#pragma unroll
            for (int j = 0; j < CPS; ++j) {
                v[k][0][j] = fbase[(size_t)j * HW + p0];
                v[k][1][j] = fbase[(size_t)j * HW + p1];
            }
        }
        __builtin_amdgcn_sched_barrier(0);       // loads above, atomics below
#pragma unroll
        for (int k = 0; k < BPT; ++k) {
            uint32_t s0 = E[k].x >> 20, s1 = E[k].y >> 20;
#pragma unroll
            for (int j = 0; j < CPS; ++j) {
                __hip_atomic_fetch_add(&sums[j * NSEG + (s0 ^ (j << 2))], v[k][0][j],
                                       __ATOMIC_RELAXED, __HIP_MEMORY_SCOPE_WORKGROUP);
                __hip_atomic_fetch_add(&sums[j * NSEG + (s1 ^ (j << 2))], v[k][1][j],
                                       __ATOMIC_RELAXED, __HIP_MEMORY_SCOPE_WORKGROUP);
            }
        }
    }
    __syncthreads();

    float* pb = partials + ((size_t)blockIdx.x) * (CPS * NSEG);
    for (int i = tid; i < CPS * NSEG; i += 1024) {
        int j = i & 3, seg = i >> 2;
        pb[i] = sums[j * NSEG + (seg ^ (j << 2))];
    }
}

// Sum the 32 range-copies (coalesced strided streams) + divide by count.
__global__ __launch_bounds__(256) void k5_red(const float* __restrict__ partials,
                                              const uint32_t* __restrict__ seghistPad,
                                              float* __restrict__ out) {
    int g = blockIdx.x * 256 + threadIdx.x;      // 0 .. 262143
    int slab = g >> 14;                          // 16384 values per slab
    int w = g & 16383;                           // w = seg*4 + j
    float s = 0.f;
#pragma unroll
    for (int r = 0; r < RANGES; ++r)
        s += partials[(((size_t)(r * SLABS + slab)) << 14) + w];
    int seg = w >> 2, j = w & 3;
    uint32_t cnt = seghistPad[seg * 16];
    out[seg * 64 + slab * 4 + j] = s / (float)(cnt ? cnt : 1u);
}

extern "C" void kernel_launch(void* const* d_in, const int* in_sizes, int n_in,
                              void* d_out, int out_size, void* d_ws, size_t ws_size,
                              hipStream_t stream) {
    const float* feat = (const float*)d_in[0];
    const int*   pix  = (const int*)d_in[1];
    const int*   seg  = (const int*)d_in[2];
    float* out = (float*)d_out;

    uint8_t* ws = (uint8_t*)d_ws;
    uint32_t* packed       = (uint32_t*)(ws);
    uint32_t* sortedPos    = (uint32_t*)(ws + (size_t)4096 * 1024);
    uint32_t* poshist      = (uint32_t*)(ws + (size_t)8192 * 1024);
    uint32_t* seghistPad   = (uint32_t*)(ws + (size_t)8448 * 1024);
    uint32_t* posLocal     = (uint32_t*)(ws + (size_t)8704 * 1024);
    uint32_t* posBlk       = (uint32_t*)(ws + (size_t)8960 * 1024);
    uint32_t* posCursorPad = (uint32_t*)(ws + (size_t)9216 * 1024);
    float*    partials     = (float*)   (ws + (size_t)13312 * 1024);

    hipMemsetAsync(poshist, 0, (size_t)512 * 1024, stream);   // poshist + seghistPad

    k1_pack_hist<<<NPIX / 512, 256, 0, stream>>>((const int4*)pix, (const int2*)seg,
                                                 (uint2*)packed, poshist, seghistPad);
    k2a_scan_local<<<64, 1024, 0, stream>>>(poshist, posLocal, posBlk);
    k2c_scan_add<<<64, 1024, 0, stream>>>(posLocal, posBlk, posCursorPad);
    k3_scatter<<<NPIX / 512, 256, 0, stream>>>((const uint2*)packed, posCursorPad, sortedPos);
    k4_accum<<<RANGES * SLABS, 1024, 0, stream>>>(feat, sortedPos, partials);
    k5_red<<<(NSEG * CCH) / 256, 256, 0, stream>>>(partials, seghistPad, out);
}

// Round 4
// 778.590 us; speedup vs baseline: 1.0015x; 1.0015x over previous
//
#include <hip/hip_runtime.h>
#include <stdint.h>

// Problem constants (fixed by setup_inputs)
#define CCH 64
#define HW  (1024 * 1024)
#define NPIX (1024 * 1024)
#define NSEG 4096
#define NBIN 65536          // pos >> 4 buckets (one 64B feature line per bucket)

#define SLABS 16            // channel slabs, CPS channels each
#define CPS 4               // channels per slab -> 4096*4*4B = 64 KB LDS accumulators
#define RANGES 32           // sorted-entry ranges (32 -> 512 blocks)
#define EPR (NPIX / RANGES) // 32768 entries per range
#define BPT 4               // uint2 (= 8 entries) per thread per iter
#define NIT (EPR / (2048 * BPT))   // 4 iterations

// ws layout (KB offsets):
//      0  packed        u32[NPIX]              4096 KB
//   4096  sortedPos     u32[NPIX]              4096 KB
//   8192  poshist       u32[NBIN]               256 KB  \ one contiguous 512 KB memset
//   8448  seghistPad    u32[NSEG*16]            256 KB  /
//   8704  posLocal      u32[NBIN]               256 KB
//   8960  posBlk        u32[64]                   4 KB
//   9216  posCursorPad  u32[NBIN*16]           4096 KB
//  13312  partials      f32[RANGES*SLABS*16384] 32768 KB
//  46080  end
#define WS_NEED ((size_t)46080 * 1024)

typedef uint32_t u32x4v __attribute__((ext_vector_type(4)));

// 128-bit buffer resource: base | stride=0 | num_records=bytes | dword-raw flags
__device__ inline u32x4v make_srsrc(const void* p, uint32_t bytes) {
    uint64_t a = (uint64_t)p;
    u32x4v r;
    r.x = (uint32_t)a;
    r.y = (uint32_t)(a >> 32);
    r.z = bytes;
    r.w = 0x00020000u;
    return r;
}

// 2 entries per thread
__global__ void k1_pack_hist(const int4* __restrict__ pix2,
                             const int2* __restrict__ seg2,
                             uint2* __restrict__ packed2,
                             uint32_t* __restrict__ poshist,
                             uint32_t* __restrict__ seghistPad) {
    int n = blockIdx.x * blockDim.x + threadIdx.x;
    int4 yx = pix2[n];                    // (y0,x0,y1,x1)
    int2 ss = seg2[n];
    uint32_t pos0 = ((uint32_t)yx.x << 10) | (uint32_t)yx.y;
    uint32_t pos1 = ((uint32_t)yx.z << 10) | (uint32_t)yx.w;
    packed2[n] = make_uint2(((uint32_t)ss.x << 20) | pos0,
                            ((uint32_t)ss.y << 20) | pos1);
    atomicAdd(&poshist[pos0 >> 4], 1u);
    atomicAdd(&poshist[pos1 >> 4], 1u);
    atomicAdd(&seghistPad[(uint32_t)ss.x * 16], 1u);
    atomicAdd(&seghistPad[(uint32_t)ss.y * 16], 1u);
}

// 64 blocks x 1024: local inclusive scan of poshist -> local EXCLUSIVE + block total
__global__ void k2a_scan_local(const uint32_t* __restrict__ poshist,
                               uint32_t* __restrict__ posLocal,
                               uint32_t* __restrict__ posBlk) {
    __shared__ uint32_t sh[1024];
    int t = threadIdx.x, b = blockIdx.x;
    int i = b * 1024 + t;
    uint32_t v = poshist[i];
    sh[t] = v;
    __syncthreads();
    for (int off = 1; off < 1024; off <<= 1) {
        uint32_t u = (t >= off) ? sh[t - off] : 0u;
        __syncthreads();
        sh[t] += u;
        __syncthreads();
    }
    uint32_t inc = sh[t];
    posLocal[i] = inc - v;
    if (t == 1023) posBlk[b] = inc;
}

// 64 blocks x 1024: each block reduces posBlk[0..b) itself,
// then final cursor = local exclusive + block base, 1 bin / 64B line
__global__ void k2c_scan_add(const uint32_t* __restrict__ posLocal,
                             const uint32_t* __restrict__ posBlk,
                             uint32_t* __restrict__ posCursorPad) {
    __shared__ uint32_t sbase;
    int t = threadIdx.x, b = blockIdx.x;
    if (t < 64) {                                // wave 0
        uint32_t v = (t < b) ? posBlk[t] : 0u;
        for (int off = 32; off; off >>= 1) v += __shfl_down(v, off);
        if (t == 0) sbase = v;
    }
    __syncthreads();
    int i = b * 1024 + t;
    posCursorPad[(size_t)i * 16] = posLocal[i] + sbase;
}

// 2 entries per thread
__global__ void k3_scatter(const uint2* __restrict__ packed2,
                           uint32_t* __restrict__ posCursorPad,
                           uint32_t* __restrict__ sorted) {
    int n = blockIdx.x * blockDim.x + threadIdx.x;
    uint2 p = packed2[n];
    uint32_t d0 = atomicAdd(&posCursorPad[(size_t)((p.x & 0xFFFFFu) >> 4) * 16], 1u);
    uint32_t d1 = atomicAdd(&posCursorPad[(size_t)((p.y & 0xFFFFFu) >> 4) * 16], 1u);
    sorted[d0] = p.x;
    sorted[d1] = p.y;
}

// Main accumulate. Block = (range, slab). MLP enforced at the ISA level:
// rounds 1-3 proved hipcc always sinks gather loads next to their consuming
// LDS atomics (VGPR stayed 24-28, k4 pinned at ~343 us = latency-serialized).
// Now the 32 gathers per iteration are asm-volatile buffer_load_dword (program
// order preserved among volatile asm -> 32 back-to-back issues, 32 results
// forced live), fenced by one s_waitcnt vmcnt(0) + sched_barrier(0) before the
// atomic batch. buffer path: voffset = pos*4 (one VGPR per entry, 32-bit since
// feat = 256 MB), channel plane via uniform SGPR soffset (slab*4+j)*4MB.
__global__ __launch_bounds__(1024) void k4_accum(const float* __restrict__ feat,
                                                 const uint32_t* __restrict__ sorted,
                                                 float* __restrict__ partials) {
    __shared__ float sums[CPS * NSEG];           // 64 KB
    const int tid = threadIdx.x;
    const int range = blockIdx.x >> 4;
    const int slab  = blockIdx.x & 15;
    for (int i = tid; i < CPS * NSEG; i += 1024) sums[i] = 0.f;

    const uint2* sp = (const uint2*)(sorted + (size_t)range * EPR);   // 16384 uint2
    const u32x4v rsrc = make_srsrc(feat, (uint32_t)CCH * HW * 4u);    // 256 MB
    const uint32_t soffBase = (uint32_t)slab * (CPS * HW * 4u);       // slab * 16 MB
    __syncthreads();

    for (int it = 0; it < NIT; ++it) {
        uint2 E[BPT];
#pragma unroll
        for (int k = 0; k < BPT; ++k)
            E[k] = sp[it * (BPT * 1024) + k * 1024 + tid];   // coalesced

        uint32_t voff[2 * BPT], segi[2 * BPT];
#pragma unroll
        for (int k = 0; k < BPT; ++k) {
            voff[2 * k]     = (E[k].x & 0xFFFFFu) << 2;
            voff[2 * k + 1] = (E[k].y & 0xFFFFFu) << 2;
            segi[2 * k]     = E[k].x >> 20;
            segi[2 * k + 1] = E[k].y >> 20;
        }

        float v[2 * BPT][CPS];
#pragma unroll
        for (int e = 0; e < 2 * BPT; ++e) {
#pragma unroll
            for (int j = 0; j < CPS; ++j) {
                asm volatile("buffer_load_dword %0, %1, %2, %3 offen"
                             : "=v"(v[e][j])
                             : "v"(voff[e]), "s"(rsrc),
                               "s"(soffBase + (uint32_t)j * (HW * 4u)));
            }
        }
        asm volatile("s_waitcnt vmcnt(0)" ::: "memory");
        __builtin_amdgcn_sched_barrier(0);

#pragma unroll
        for (int e = 0; e < 2 * BPT; ++e) {
#pragma unroll
            for (int j = 0; j < CPS; ++j) {
                __hip_atomic_fetch_add(&sums[j * NSEG + (segi[e] ^ (j << 2))], v[e][j],
                                       __ATOMIC_RELAXED, __HIP_MEMORY_SCOPE_WORKGROUP);
            }
        }
    }
    __syncthreads();

    float* pb = partials + ((size_t)blockIdx.x) * (CPS * NSEG);
    for (int i = tid; i < CPS * NSEG; i += 1024) {
        int j = i & 3, seg = i >> 2;
        pb[i] = sums[j * NSEG + (seg ^ (j << 2))];
    }
}

// Sum the 32 range-copies (coalesced strided streams) + divide by count.
__global__ __launch_bounds__(256) void k5_red(const float* __restrict__ partials,
                                              const uint32_t* __restrict__ seghistPad,
                                              float* __restrict__ out) {
    int g = blockIdx.x * 256 + threadIdx.x;      // 0 .. 262143
    int slab = g >> 14;                          // 16384 values per slab
    int w = g & 16383;                           // w = seg*4 + j
    float s = 0.f;
#pragma unroll
    for (int r = 0; r < RANGES; ++r)
        s += partials[(((size_t)(r * SLABS + slab)) << 14) + w];
    int seg = w >> 2, j = w & 3;
    uint32_t cnt = seghistPad[seg * 16];
    out[seg * 64 + slab * 4 + j] = s / (float)(cnt ? cnt : 1u);
}

extern "C" void kernel_launch(void* const* d_in, const int* in_sizes, int n_in,
                              void* d_out, int out_size, void* d_ws, size_t ws_size,
                              hipStream_t stream) {
    const float* feat = (const float*)d_in[0];
    const int*   pix  = (const int*)d_in[1];
    const int*   seg  = (const int*)d_in[2];
    float* out = (float*)d_out;

    uint8_t* ws = (uint8_t*)d_ws;
    uint32_t* packed       = (uint32_t*)(ws);
    uint32_t* sortedPos    = (uint32_t*)(ws + (size_t)4096 * 1024);
    uint32_t* poshist      = (uint32_t*)(ws + (size_t)8192 * 1024);
    uint32_t* seghistPad   = (uint32_t*)(ws + (size_t)8448 * 1024);
    uint32_t* posLocal     = (uint32_t*)(ws + (size_t)8704 * 1024);
    uint32_t* posBlk       = (uint32_t*)(ws + (size_t)8960 * 1024);
    uint32_t* posCursorPad = (uint32_t*)(ws + (size_t)9216 * 1024);
    float*    partials     = (float*)   (ws + (size_t)13312 * 1024);

    hipMemsetAsync(poshist, 0, (size_t)512 * 1024, stream);   // poshist + seghistPad

    k1_pack_hist<<<NPIX / 512, 256, 0, stream>>>((const int4*)pix, (const int2*)seg,
                                                 (uint2*)packed, poshist, seghistPad);
    k2a_scan_local<<<64, 1024, 0, stream>>>(poshist, posLocal, posBlk);
    k2c_scan_add<<<64, 1024, 0, stream>>>(posLocal, posBlk, posCursorPad);
    k3_scatter<<<NPIX / 512, 256, 0, stream>>>((const uint2*)packed, posCursorPad, sortedPos);
    k4_accum<<<RANGES * SLABS, 1024, 0, stream>>>(feat, sortedPos, partials);
    k5_red<<<(NSEG * CCH) / 256, 256, 0, stream>>>(partials, seghistPad, out);
}

// Round 5
// 595.460 us; speedup vs baseline: 1.3095x; 1.3075x over previous
//
#include <hip/hip_runtime.h>
#include <stdint.h>

// Problem constants (fixed by setup_inputs)
#define CCH 64
#define HW  (1024 * 1024)
#define NPIX (1024 * 1024)
#define NSEG 4096
#define NBIN 65536          // pos >> 4 buckets (one 64B feature line per bucket)

typedef uint32_t u32x4 __attribute__((ext_vector_type(4)));

// ws layout (KB offsets):
//      0  packed        u32[NPIX]        4096 KB
//   4096  sortedPos     u32[NPIX]        4096 KB
//   8192  poshist       u32[NBIN]         256 KB   \ one contiguous 512 KB memset
//   8448  seghistPad    u32[NSEG*16]      256 KB   /
//   8704  posLocal      u32[NBIN]         256 KB
//   8960  posBlk        u32[64]             4 KB
//   8964  posBlkExc     u32[64]             4 KB
//   8968  segOff        u32[NSEG]          16 KB
//   9216  segCursorPad  u32[NSEG*16]      256 KB
//  10240  posCursorPad  u32[NBIN*16]     4096 KB
//  16384  gathered      u32[NPIX*32]   131072 KB  (bf16-pair packed rows, 128 MB)
#define WS_NEED ((size_t)147456 * 1024)

// SESSION NOTE (rounds 1-4): LDS-accumulator variants (seg-indexed ds_add_f32)
// are pinned at 344 us regardless of load scheduling / occupancy / asm batching.
// 64M divergent-address lane-atomics = 211 cy per wave-level ds_add (~3.3 cy/lane,
// per-lane-serial LDS RMW). Do NOT reintroduce bulk LDS float atomics.

__device__ inline uint32_t pack_bf16(float a, float b) {
    uint32_t ua = __float_as_uint(a), ub = __float_as_uint(b);
    ua = (ua + 0x7FFFu + ((ua >> 16) & 1u)) >> 16;   // RNE
    ub = (ub + 0x7FFFu + ((ub >> 16) & 1u)) >> 16;
    return (ub << 16) | ua;                           // lo = ch 2k, hi = ch 2k+1
}
__device__ inline float bf_lo(uint32_t v) { return __uint_as_float(v << 16); }
__device__ inline float bf_hi(uint32_t v) { return __uint_as_float(v & 0xFFFF0000u); }

// 2 entries per thread
__global__ void k1_pack_hist(const int4* __restrict__ pix2,
                             const int2* __restrict__ seg2,
                             uint2* __restrict__ packed2,
                             uint32_t* __restrict__ poshist,
                             uint32_t* __restrict__ seghistPad) {
    int n = blockIdx.x * blockDim.x + threadIdx.x;
    int4 yx = pix2[n];                    // (y0,x0,y1,x1)
    int2 ss = seg2[n];
    uint32_t pos0 = ((uint32_t)yx.x << 10) | (uint32_t)yx.y;
    uint32_t pos1 = ((uint32_t)yx.z << 10) | (uint32_t)yx.w;
    packed2[n] = make_uint2(((uint32_t)ss.x << 20) | pos0,
                            ((uint32_t)ss.y << 20) | pos1);
    atomicAdd(&poshist[pos0 >> 4], 1u);
    atomicAdd(&poshist[pos1 >> 4], 1u);
    atomicAdd(&seghistPad[(uint32_t)ss.x * 16], 1u);
    atomicAdd(&seghistPad[(uint32_t)ss.y * 16], 1u);
}

// 64 blocks x 1024: local inclusive scan of poshist -> local EXCLUSIVE + block total
__global__ void k2a_scan_local(const uint32_t* __restrict__ poshist,
                               uint32_t* __restrict__ posLocal,
                               uint32_t* __restrict__ posBlk) {
    __shared__ uint32_t sh[1024];
    int t = threadIdx.x, b = blockIdx.x;
    int i = b * 1024 + t;
    uint32_t v = poshist[i];
    sh[t] = v;
    __syncthreads();
    for (int off = 1; off < 1024; off <<= 1) {
        uint32_t u = (t >= off) ? sh[t - off] : 0u;
        __syncthreads();
        sh[t] += u;
        __syncthreads();
    }
    uint32_t inc = sh[t];
    posLocal[i] = inc - v;
    if (t == 1023) posBlk[b] = inc;
}

// 1 block x 1024: scan 64 block totals (wave 0) + scan seghist (4 bins/thread)
__global__ void k2b_scan_tops(const uint32_t* __restrict__ posBlk,
                              uint32_t* __restrict__ posBlkExc,
                              const uint32_t* __restrict__ seghistPad,
                              uint32_t* __restrict__ segOff,
                              uint32_t* __restrict__ segCursorPad) {
    int t = threadIdx.x;
    if (t < 64) {
        uint32_t v = posBlk[t];
        uint32_t x = v;
        for (int off = 1; off < 64; off <<= 1) {
            uint32_t u = __shfl_up(x, off);
            if ((t & 63) >= off) x += u;
        }
        posBlkExc[t] = x - v;
    }
    uint32_t c0 = seghistPad[(4 * t + 0) * 16];
    uint32_t c1 = seghistPad[(4 * t + 1) * 16];
    uint32_t c2 = seghistPad[(4 * t + 2) * 16];
    uint32_t c3 = seghistPad[(4 * t + 3) * 16];
    uint32_t tot = c0 + c1 + c2 + c3;
    __shared__ uint32_t sh[1024];
    sh[t] = tot;
    __syncthreads();
    for (int off = 1; off < 1024; off <<= 1) {
        uint32_t u = (t >= off) ? sh[t - off] : 0u;
        __syncthreads();
        sh[t] += u;
        __syncthreads();
    }
    uint32_t base = sh[t] - tot;
    uint32_t o0 = base, o1 = base + c0, o2 = o1 + c1, o3 = o2 + c2;
    ((uint4*)segOff)[t] = make_uint4(o0, o1, o2, o3);
    segCursorPad[(4 * t + 0) * 16] = o0;
    segCursorPad[(4 * t + 1) * 16] = o1;
    segCursorPad[(4 * t + 2) * 16] = o2;
    segCursorPad[(4 * t + 3) * 16] = o3;
}

// 64 blocks x 1024: final cursor = local exclusive + block offset, 1 bin / 64B line
__global__ void k2c_scan_add(const uint32_t* __restrict__ posLocal,
                             const uint32_t* __restrict__ posBlkExc,
                             uint32_t* __restrict__ posCursorPad) {
    int t = threadIdx.x, b = blockIdx.x;
    int i = b * 1024 + t;
    posCursorPad[(size_t)i * 16] = posLocal[i] + posBlkExc[b];
}

// 2 entries per thread
__global__ void k3_scatter(const uint2* __restrict__ packed2,
                           uint32_t* __restrict__ posCursorPad,
                           uint32_t* __restrict__ sorted) {
    int n = blockIdx.x * blockDim.x + threadIdx.x;
    uint2 p = packed2[n];
    uint32_t d0 = atomicAdd(&posCursorPad[(size_t)((p.x & 0xFFFFFu) >> 4) * 16], 1u);
    uint32_t d1 = atomicAdd(&posCursorPad[(size_t)((p.y & 0xFFFFFu) >> 4) * 16], 1u);
    sorted[d0] = p.x;
    sorted[d1] = p.y;
}

// Main gather. MLP-first structure: all 64 plane loads issued into a register
// array BEFORE any pack/LDS op (64 outstanding vector loads/lane = vmcnt cap),
// then pack bf16 pairs -> LDS (stride 36: 16B-aligned rows, even bank spread),
// then 8-lanes-per-row coalesced nontemporal stores (full 128B rows).
// feat/sorted loads are nontemporal: feat is once-through (256 MB), keep L2/LLC
// for cursor tables + gathered.
__global__ __launch_bounds__(256) void k4_gather(const float* __restrict__ feat,
                                                 const uint32_t* __restrict__ sorted,
                                                 uint32_t* __restrict__ segCursorPad,
                                                 uint32_t* __restrict__ gathered) {
    __shared__ uint32_t tile[256 * 36];
    __shared__ uint32_t rnk[256];
    const int tid = threadIdx.x;
    const int idx = blockIdx.x * 256 + tid;

    uint32_t pk = __builtin_nontemporal_load(&sorted[idx]);
    const float* fp = feat + (pk & 0xFFFFFu);
    rnk[tid] = atomicAdd(&segCursorPad[(pk >> 20) * 16], 1u);

    float v[64];
#pragma unroll
    for (int c = 0; c < 64; ++c) {
        v[c] = __builtin_nontemporal_load(&fp[(size_t)c * HW]);  // independent, stay in flight
    }
#pragma unroll
    for (int j = 0; j < 8; ++j) {
        u32x4 q = { pack_bf16(v[8 * j + 0], v[8 * j + 1]),
                    pack_bf16(v[8 * j + 2], v[8 * j + 3]),
                    pack_bf16(v[8 * j + 4], v[8 * j + 5]),
                    pack_bf16(v[8 * j + 6], v[8 * j + 7]) };
        *(u32x4*)&tile[tid * 36 + j * 4] = q;
    }
    __syncthreads();

    const int sub = tid & 7;        // 16B chunk within row
    const int rg  = tid >> 3;       // row group 0..31
#pragma unroll
    for (int it = 0; it < 8; ++it) {
        int row = it * 32 + rg;
        uint32_t r = rnk[row];
        u32x4 q = *(const u32x4*)&tile[row * 36 + sub * 4];
        __builtin_nontemporal_store(q, (u32x4*)(gathered + (size_t)r * 32 + sub * 4));
    }
}

// One block per segment: stream contiguous rows with u32x4 loads, reduce, divide.
__global__ __launch_bounds__(256) void k5_reduce(const uint32_t* __restrict__ gathered,
                                                 const uint32_t* __restrict__ segOff,
                                                 const uint32_t* __restrict__ seghistPad,
                                                 float* __restrict__ out) {
    const int s = blockIdx.x;
    const int tid = threadIdx.x;
    const int ch = tid & 7;        // 16B chunk (channels 8ch..8ch+7)
    const int rg = tid >> 3;       // row-group 0..31
    uint32_t base = segOff[s];
    uint32_t cnt = seghistPad[s * 16];
    float acc[8] = {0.f, 0.f, 0.f, 0.f, 0.f, 0.f, 0.f, 0.f};
    const u32x4* g4 = (const u32x4*)gathered;
    for (uint32_t r = rg; r < cnt; r += 32) {
        u32x4 v = __builtin_nontemporal_load(&g4[(size_t)(base + r) * 8 + ch]);
        acc[0] += bf_lo(v.x); acc[1] += bf_hi(v.x);
        acc[2] += bf_lo(v.y); acc[3] += bf_hi(v.y);
        acc[4] += bf_lo(v.z); acc[5] += bf_hi(v.z);
        acc[6] += bf_lo(v.w); acc[7] += bf_hi(v.w);
    }
    __shared__ float red[256][8];
#pragma unroll
    for (int j = 0; j < 8; ++j) red[tid][j] = acc[j];
    __syncthreads();
    if (tid < 64) {                 // thread = channel
        int chunk = tid >> 3, j = tid & 7;
        float sum = 0.f;
#pragma unroll
        for (int g = 0; g < 32; ++g) sum += red[g * 8 + chunk][j];
        float inv = 1.0f / (float)(cnt ? cnt : 1u);
        out[s * 64 + tid] = sum * inv;
    }
}

// ---------- fallback path (small ws): direct-atomic kernel ----------
__global__ __launch_bounds__(256) void k4_stream(const float* __restrict__ feat,
                                                 const uint32_t* __restrict__ sorted,
                                                 float* __restrict__ sums) {
    __shared__ float tile[64 * 65];
    __shared__ uint32_t epack[1024];
    const int tid = threadIdx.x;
    const int w = tid >> 6;
    const int l = tid & 63;
    const int base = blockIdx.x * 1024;
    for (int i = tid; i < 1024; i += 256) epack[i] = sorted[base + i];
    __syncthreads();
    for (int t = 0; t < 16; ++t) {
        uint32_t pk = epack[t * 64 + l];
        const float* fp = feat + (pk & 0xFFFFFu);
#pragma unroll
        for (int cc = 0; cc < 16; ++cc) {
            int c = (w << 4) + cc;
            tile[l * 65 + c] = fp[(size_t)c * HW];
        }
        __syncthreads();
#pragma unroll
        for (int pp = 0; pp < 16; ++pp) {
            int p = (w << 4) + pp;
            uint32_t sg = epack[t * 64 + p] >> 20;
            atomicAdd(&sums[sg * 64 + l], tile[p * 65 + l]);
        }
        __syncthreads();
    }
}

__global__ void k5_div(float* __restrict__ out, const uint32_t* __restrict__ seghistPad) {
    int i = blockIdx.x * blockDim.x + threadIdx.x;
    uint32_t cnt = seghistPad[(i >> 6) * 16];
    float c = (float)(cnt ? cnt : 1u);
    out[i] = out[i] / c;
}

extern "C" void kernel_launch(void* const* d_in, const int* in_sizes, int n_in,
                              void* d_out, int out_size, void* d_ws, size_t ws_size,
                              hipStream_t stream) {
    const float* feat = (const float*)d_in[0];
    const int*   pix  = (const int*)d_in[1];
    const int*   seg  = (const int*)d_in[2];
    float* out = (float*)d_out;

    uint8_t* ws = (uint8_t*)d_ws;
    uint32_t* packed       = (uint32_t*)(ws);
    uint32_t* sortedPos    = (uint32_t*)(ws + (size_t)4096 * 1024);
    uint32_t* poshist      = (uint32_t*)(ws + (size_t)8192 * 1024);
    uint32_t* seghistPad   = (uint32_t*)(ws + (size_t)8448 * 1024);
    uint32_t* posLocal     = (uint32_t*)(ws + (size_t)8704 * 1024);
    uint32_t* posBlk       = (uint32_t*)(ws + (size_t)8960 * 1024);
    uint32_t* posBlkExc    = (uint32_t*)(ws + (size_t)8964 * 1024);
    uint32_t* segOff       = (uint32_t*)(ws + (size_t)8968 * 1024);
    uint32_t* segCursorPad = (uint32_t*)(ws + (size_t)9216 * 1024);
    uint32_t* posCursorPad = (uint32_t*)(ws + (size_t)10240 * 1024);
    uint32_t* gathered     = (uint32_t*)(ws + (size_t)16384 * 1024);

    hipMemsetAsync(poshist, 0, (size_t)512 * 1024, stream);   // poshist + seghistPad

    k1_pack_hist<<<NPIX / 512, 256, 0, stream>>>((const int4*)pix, (const int2*)seg,
                                                 (uint2*)packed, poshist, seghistPad);
    k2a_scan_local<<<64, 1024, 0, stream>>>(poshist, posLocal, posBlk);
    k2b_scan_tops<<<1, 1024, 0, stream>>>(posBlk, posBlkExc, seghistPad, segOff, segCursorPad);
    k2c_scan_add<<<64, 1024, 0, stream>>>(posLocal, posBlkExc, posCursorPad);
    k3_scatter<<<NPIX / 512, 256, 0, stream>>>((const uint2*)packed, posCursorPad, sortedPos);

    if (ws_size >= WS_NEED) {
        // k5_reduce fully overwrites out -> no out memset needed on this path
        k4_gather<<<NPIX / 256, 256, 0, stream>>>(feat, sortedPos, segCursorPad, gathered);
        k5_reduce<<<NSEG, 256, 0, stream>>>(gathered, segOff, seghistPad, out);
    } else {
        hipMemsetAsync(out, 0, (size_t)NSEG * CCH * sizeof(float), stream);
        k4_stream<<<NPIX / 1024, 256, 0, stream>>>(feat, sortedPos, out);
        k5_div<<<(NSEG * CCH) / 256, 256, 0, stream>>>(out, seghistPad);
    }
}